// Round 2
// baseline (443.891 us; speedup 1.0000x reference)
//
#include <hip/hip_runtime.h>

#define SINKHORN_ITERS 20
#define N_STREAMS 4
#define DDIM 1024
#define BT_PER_BLOCK 8   // amortizes per-wave sinkhorn; 2048 blocks = 8 blocks/CU

// Fused kernel: every wave redundantly computes sinkhorn(H_raw) (4x4, 16
// floats) via lane-parallel xor-shuffles — deterministic fp ops, so all waves
// get bit-identical H; no cross-block dependency, no second launch.
//
// Lane k (mod 16) holds A[i][j] with i=(k>>2)&3, j=k&3. Row sum (over j)
// = butterfly over lane bits 0-1; col sum (over i) = butterfly over bits 2-3.
// Lanes 16..63 carry replicas, so the 16-lane butterflies stay closed.
//
// Then streams: out[bt,n,d] = sum_m H[n][m] * x[bt,m,d], one thread per
// (bt, d/4) float4, 8 bt per block. Consecutive lanes -> consecutive float4
// inside a 4 KiB stream chunk: 1 KiB/wave per vmem instruction, fully
// coalesced, every byte touched exactly once.
__global__ __launch_bounds__(256) void fused_mix_k(const float* __restrict__ x,
                                                   const float* __restrict__ H_raw,
                                                   float* __restrict__ out,
                                                   int n_bt) {
    const int tid = threadIdx.x;
    const int lane = tid & 63;

    // ---- per-wave sinkhorn (hides under first global loads / launch) ----
    float A = fabsf(H_raw[lane & 15]) + 1e-8f;
#pragma unroll 1
    for (int it = 0; it < SINKHORN_ITERS; ++it) {
        float r1 = A + __shfl_xor(A, 1);
        float rs = r1 + __shfl_xor(r1, 2);   // row sum (axis=1)
        A = A / rs;
        float c1 = A + __shfl_xor(A, 4);
        float cs = c1 + __shfl_xor(c1, 8);   // col sum (axis=0)
        A = A / cs;
    }
    float h[16];
#pragma unroll
    for (int k = 0; k < 16; ++k) h[k] = __shfl(A, k);  // h[n*4+m] from lane n*4+m

    // ---- streaming mix ----
    const int C = DDIM / 4;          // 256 float4 per (bt, stream) chunk
    const int dv = tid;              // 0..255: float4 index within a chunk
    int bt0 = blockIdx.x * BT_PER_BLOCK;

#pragma unroll 1
    for (int g = 0; g < BT_PER_BLOCK; ++g) {
        int bt = bt0 + g;
        if (bt >= n_bt) break;
        const float4* xp = (const float4*)x + (size_t)bt * (N_STREAMS * C) + dv;
        float4* op = (float4*)out + (size_t)bt * (N_STREAMS * C) + dv;

        float4 x0 = xp[0 * C];
        float4 x1 = xp[1 * C];
        float4 x2 = xp[2 * C];
        float4 x3 = xp[3 * C];

#pragma unroll
        for (int n = 0; n < 4; ++n) {
            float4 o;
            o.x = h[n*4+0]*x0.x + h[n*4+1]*x1.x + h[n*4+2]*x2.x + h[n*4+3]*x3.x;
            o.y = h[n*4+0]*x0.y + h[n*4+1]*x1.y + h[n*4+2]*x2.y + h[n*4+3]*x3.y;
            o.z = h[n*4+0]*x0.z + h[n*4+1]*x1.z + h[n*4+2]*x2.z + h[n*4+3]*x3.z;
            o.w = h[n*4+0]*x0.w + h[n*4+1]*x1.w + h[n*4+2]*x2.w + h[n*4+3]*x3.w;
            op[n * C] = o;
        }
    }
}

extern "C" void kernel_launch(void* const* d_in, const int* in_sizes, int n_in,
                              void* d_out, int out_size, void* d_ws, size_t ws_size,
                              hipStream_t stream) {
    const float* x = (const float*)d_in[0];
    const float* H_raw = (const float*)d_in[1];
    float* out = (float*)d_out;

    int n_bt = in_sizes[0] / (N_STREAMS * DDIM);      // = B*T = 16384
    int blocks = (n_bt + BT_PER_BLOCK - 1) / BT_PER_BLOCK;  // = 2048
    fused_mix_k<<<blocks, 256, 0, stream>>>(x, H_raw, out, n_bt);
}

// Round 4
// 436.253 us; speedup vs baseline: 1.0175x; 1.0175x over previous
//
#include <hip/hip_runtime.h>

#define SINKHORN_ITERS 20
#define N_STREAMS 4
#define DDIM 1024
#define BT_PER_BLOCK 8   // 2048 blocks = 8 blocks/CU; 8192 waves = full CU wave capacity

// Native clang vector type — HIP's float4 is a class and is rejected by
// __builtin_nontemporal_load/store; this lowers identically to dwordx4.
typedef float f32x4 __attribute__((ext_vector_type(4)));

// Fused kernel: every wave redundantly computes sinkhorn(H_raw) (4x4) via
// lane-parallel xor-shuffles (bit-identical across waves), then streams
// out[bt,n,d] = sum_m H[n][m] * x[bt,m,d].
//
// Memory: x is L3-COLD here (the harness's 1 GB d_ws poison runs after the
// x-restore and evicts all of L3), and out is never re-read — so both sides
// use nontemporal accesses to skip cache allocation on use-once streams.
// Lane-consecutive float4 within a 4 KiB stream chunk: 1 KiB/wave per vmem
// instruction, fully coalesced, every byte touched exactly once.
__global__ __launch_bounds__(256) void fused_mix_k(const float* __restrict__ x,
                                                   const float* __restrict__ H_raw,
                                                   float* __restrict__ out,
                                                   int n_bt) {
    const int tid = threadIdx.x;
    const int lane = tid & 63;

    // ---- per-wave sinkhorn (~1.4k cycles, hides under first global loads) ----
    // Lane k holds A[i][j], i=(k>>2)&3, j=k&3; lanes 16..63 carry replicas so
    // the 16-lane butterflies stay closed.
    float A = fabsf(H_raw[lane & 15]) + 1e-8f;
#pragma unroll 1
    for (int it = 0; it < SINKHORN_ITERS; ++it) {
        float r1 = A + __shfl_xor(A, 1);
        float rs = r1 + __shfl_xor(r1, 2);   // row sum (axis=1)
        A = A / rs;
        float c1 = A + __shfl_xor(A, 4);
        float cs = c1 + __shfl_xor(c1, 8);   // col sum (axis=0)
        A = A / cs;
    }
    float h[16];
#pragma unroll
    for (int k = 0; k < 16; ++k) h[k] = __shfl(A, k);  // h[n*4+m] from lane n*4+m

    // ---- streaming mix ----
    const int C = DDIM / 4;          // 256 float4 per (bt, stream) chunk
    const int dv = tid;              // 0..255: float4 index within a chunk
    int bt0 = blockIdx.x * BT_PER_BLOCK;

#pragma unroll 1
    for (int g = 0; g < BT_PER_BLOCK; ++g) {
        int bt = bt0 + g;
        if (bt >= n_bt) break;
        const f32x4* xp = (const f32x4*)x + (size_t)bt * (N_STREAMS * C) + dv;
        f32x4* op = (f32x4*)out + (size_t)bt * (N_STREAMS * C) + dv;

        f32x4 x0 = __builtin_nontemporal_load(xp + 0 * C);
        f32x4 x1 = __builtin_nontemporal_load(xp + 1 * C);
        f32x4 x2 = __builtin_nontemporal_load(xp + 2 * C);
        f32x4 x3 = __builtin_nontemporal_load(xp + 3 * C);

#pragma unroll
        for (int n = 0; n < 4; ++n) {
            f32x4 o = h[n*4+0] * x0 + h[n*4+1] * x1 + h[n*4+2] * x2 + h[n*4+3] * x3;
            __builtin_nontemporal_store(o, op + n * C);
        }
    }
}

extern "C" void kernel_launch(void* const* d_in, const int* in_sizes, int n_in,
                              void* d_out, int out_size, void* d_ws, size_t ws_size,
                              hipStream_t stream) {
    const float* x = (const float*)d_in[0];
    const float* H_raw = (const float*)d_in[1];
    float* out = (float*)d_out;

    int n_bt = in_sizes[0] / (N_STREAMS * DDIM);            // = B*T = 16384
    int blocks = (n_bt + BT_PER_BLOCK - 1) / BT_PER_BLOCK;  // = 2048
    fused_mix_k<<<blocks, 256, 0, stream>>>(x, H_raw, out, n_bt);
}